// Round 9
// baseline (166.343 us; speedup 1.0000x reference)
//
#include <hip/hip_runtime.h>
#include <hip/hip_bf16.h>
#include <stdint.h>

#define Bn 8192
#define Dk 512
#define SCALE1 0x7F7F7F7F   // e8m0 127 (=1.0) in every byte: opsel-proof

typedef __attribute__((ext_vector_type(8))) int   int8v;
typedef __attribute__((ext_vector_type(4))) int   int4v;
typedef __attribute__((ext_vector_type(16))) float f32x16;

// async global -> LDS, 16 bytes per lane (dest = wave-uniform base + lane*16)
__device__ __forceinline__ void gload_lds16(const uint8_t* g, const uint8_t* l) {
  __builtin_amdgcn_global_load_lds(
      (const __attribute__((address_space(1))) void*)g,
      (__attribute__((address_space(3))) void*)l,
      16, 0, 0);
}

// ---------------------------------------------------------------------------
// Kernel 1: cast fp32 embeddings to fp8 e4m3 + exact fp32 row norms.
// ---------------------------------------------------------------------------
__global__ __launch_bounds__(128) void prep_kernel(
    const float* __restrict__ T, const float* __restrict__ M,
    uint8_t* __restrict__ Tq, uint8_t* __restrict__ Mq,
    float* __restrict__ tn, float* __restrict__ mn)
{
  const int bid = blockIdx.x;
  const int row = bid & (Bn - 1);
  const bool isM = bid >= Bn;
  const float* __restrict__ src = isM ? M : T;
  unsigned* __restrict__ dst = (unsigned*)(isM ? Mq : Tq);
  const int tid = threadIdx.x;

  float4 v = reinterpret_cast<const float4*>(src + (size_t)row * Dk)[tid];
  float s = v.x * v.x + v.y * v.y + v.z * v.z + v.w * v.w;
  int p = __builtin_amdgcn_cvt_pk_fp8_f32(v.x, v.y, 0, false);
  p = __builtin_amdgcn_cvt_pk_fp8_f32(v.z, v.w, p, true);
  dst[(size_t)row * 128 + tid] = (unsigned)p;

  #pragma unroll
  for (int off = 32; off >= 1; off >>= 1) s += __shfl_xor(s, off, 64);
  __shared__ float ws2[2];
  if ((tid & 63) == 0) ws2[tid >> 6] = s;
  __syncthreads();
  if (tid == 0) (isM ? mn : tn)[row] = ws2[0] + ws2[1];
}

// ---------------------------------------------------------------------------
// Kernel 2: 256x128-tile MX-fp8 GEMM (scale=1.0), BK=64, ring-2 LDS (51 KB
// -> 2 blocks/CU; regs capped by __launch_bounds__(512,4) so 16 waves/CU).
// 8 waves (4 text-cols x 2 image-rows), wave tile 64x64, acc = 64 f32.
// Conflict-free LDS permutation (both-sides, rule #21): chunk (row r, slot s)
// of a 64B-row K-tile lives at chunk-index (r>>5)*128+(s&1)*64+(s>>1)*32+(r&31),
// achieved by permuting the per-lane GLOBAL source (dest stays linear).
// A wave's fragment read (lo: +h*512+l31*16, hi: +1024) is then a contiguous
// 1024 B block = the zero-conflict pattern. Counted vmcnt(3), 1 barrier/step.
// ---------------------------------------------------------------------------
__global__ __launch_bounds__(512, 4) void gemm_epi_kernel(
    const uint8_t* __restrict__ Tq, const uint8_t* __restrict__ Mq,
    const float* __restrict__ tn, const float* __restrict__ mn,
    const int* __restrict__ groups,
    float2* __restrict__ part)
{
  extern __shared__ char smem[];
  uint8_t* As8 = (uint8_t*)smem;             // text tiles: 2 bufs x 256x64 fp8
  uint8_t* Bs8 = As8 + 2 * 16384;            // image tiles: 2 bufs x 128x64
  float2* tg_s = (float2*)(Bs8 + 2 * 8192);  // 256 (text norm, group bits)
  float2* mg_s = tg_s + 256;                 // 128 (image norm, group bits)

  const int tid = threadIdx.x;
  const int wave = tid >> 6;
  const int lane = tid & 63;
  const int l31 = lane & 31, h = lane >> 5;

  // XCD-compact swizzle: 2048 blocks = 8 XCDs x (4 by x 64 bx)
  const int bid = blockIdx.x;
  const int xcd = bid & 7, lidx = bid >> 3;      // lidx 0..255
  const int by = xcd * 4 + (lidx >> 6);          // 0..31  (text panel, 256 rows)
  const int bx = lidx & 63;                      // 0..63  (image panel, 128 rows)
  const int brow = by * 256;
  const int bcol = bx * 128;

  const int tc = wave & 3;     // text quarter: rows tc*64 .. +64
  const int ir = wave >> 2;    // image half:  rows ir*64 .. +64

  // staging geometry: permuted global source, linear LDS dest.
  // text: 1024 chunks (2/thread); image: 512 chunks (1/thread).
  unsigned goffT[2], goffM;
  int ldsT[2], ldsM;
  #pragma unroll
  for (int i = 0; i < 2; ++i) {
    const int c = i * 512 + tid;
    const int cc = c & 127;
    const int s = (((cc >> 5) & 1) << 1) | ((cc >> 6) & 1);
    const int r = (c >> 7) * 32 + (cc & 31);
    goffT[i] = (unsigned)(brow + r) * Dk + s * 16;
    ldsT[i] = (i * 512 + wave * 64) * 16;
  }
  {
    const int c = tid;
    const int cc = c & 127;
    const int s = (((cc >> 5) & 1) << 1) | ((cc >> 6) & 1);
    const int r = (c >> 7) * 32 + (cc & 31);
    goffM = (unsigned)(bcol + r) * Dk + s * 16;
    ldsM = wave * 64 * 16;
  }

  auto stage = [&](int t, int buf) {
    const int k0 = t * 64;
    gload_lds16(Tq + goffT[0] + k0, As8 + buf * 16384 + ldsT[0]);
    gload_lds16(Tq + goffT[1] + k0, As8 + buf * 16384 + ldsT[1]);
    gload_lds16(Mq + goffM + k0, Bs8 + buf * 8192 + ldsM);
  };

  // fragment read offsets (kt-independent): contiguous-1024B wave reads
  int toffB[2], moffB[2];
  #pragma unroll
  for (int jt = 0; jt < 2; ++jt)
    toffB[jt] = (tc * 2 + jt) * 2048 + h * 512 + l31 * 16;
  #pragma unroll
  for (int it = 0; it < 2; ++it)
    moffB[it] = (ir * 2 + it) * 2048 + h * 512 + l31 * 16;

  f32x16 acc[2][2];
  #pragma unroll
  for (int it = 0; it < 2; ++it)
    #pragma unroll
    for (int jt = 0; jt < 2; ++jt)
      #pragma unroll
      for (int e = 0; e < 16; ++e)
        acc[it][jt][e] = 0.f;

  stage(0, 0);
  int kt = 0;

#define STEP(BUF, DO_STAGE, VMC)                                               \
  do {                                                                         \
    __builtin_amdgcn_s_barrier();                                              \
    if (DO_STAGE) stage(kt + 1, (BUF) ^ 1);                                    \
    asm volatile("s_waitcnt vmcnt(" #VMC ")" ::: "memory");                    \
    int8v tf[2], mf[2];                                                        \
    _Pragma("unroll")                                                          \
    for (int jt = 0; jt < 2; ++jt) {                                           \
      int4v lo = *(const int4v*)(As8 + (BUF) * 16384 + toffB[jt]);             \
      int4v hi = *(const int4v*)(As8 + (BUF) * 16384 + toffB[jt] + 1024);      \
      tf[jt] = __builtin_shufflevector(lo, hi, 0, 1, 2, 3, 4, 5, 6, 7);        \
    }                                                                          \
    _Pragma("unroll")                                                          \
    for (int it = 0; it < 2; ++it) {                                           \
      int4v lo = *(const int4v*)(Bs8 + (BUF) * 8192 + moffB[it]);              \
      int4v hi = *(const int4v*)(Bs8 + (BUF) * 8192 + moffB[it] + 1024);       \
      mf[it] = __builtin_shufflevector(lo, hi, 0, 1, 2, 3, 4, 5, 6, 7);        \
    }                                                                          \
    __builtin_amdgcn_s_setprio(1);                                             \
    _Pragma("unroll")                                                          \
    for (int it = 0; it < 2; ++it)                                             \
      _Pragma("unroll")                                                        \
      for (int jt = 0; jt < 2; ++jt)                                           \
        acc[it][jt] = __builtin_amdgcn_mfma_scale_f32_32x32x64_f8f6f4(         \
            mf[it], tf[jt], acc[it][jt], 0, 0, 0, SCALE1, 0, SCALE1);          \
    __builtin_amdgcn_s_setprio(0);                                             \
    ++kt;                                                                      \
  } while (0)

  STEP(0, true, 3); STEP(1, true, 3); STEP(0, true, 3); STEP(1, true, 3);
  STEP(0, true, 3); STEP(1, true, 3); STEP(0, true, 3); STEP(1, false, 0);
#undef STEP

  // ---- fused epilogue (no atomics) ----
  // acc[it][jt][reg] on lane (l31,h) = dot(image[bcol+ir*64+it*32+crow],
  //                                        text [brow+tc*64+jt*32+l31])
  // crow = (reg&3) + 8*(reg>>2) + 4*h.
  if (tid < 256) {
    tg_s[tid] = make_float2(tn[brow + tid], __uint_as_float((unsigned)groups[brow + tid]));
  } else if (tid < 384) {
    const int t = tid - 256;
    mg_s[t] = make_float2(mn[bcol + t], __uint_as_float((unsigned)groups[bcol + t]));
  }
  __syncthreads();   // norm fill visible + all tile-buf reads complete CU-wide

  float2* red = reinterpret_cast<float2*>(As8);   // 8 KB alias on buf0 (dead)

  #pragma unroll
  for (int jt = 0; jt < 2; ++jt) {
    const int tl = tc * 64 + jt * 32 + l31;
    const float2 tg = tg_s[tl];
    const unsigned gt = __float_as_uint(tg.y);
    float nv = 0.f, dv = 0.f;
    #pragma unroll
    for (int it = 0; it < 2; ++it) {
      #pragma unroll
      for (int reg = 0; reg < 16; ++reg) {
        const int crow = (reg & 3) + 8 * (reg >> 2) + 4 * h;
        const float2 mg = mg_s[ir * 64 + it * 32 + crow];
        const float sq = fmaxf(tg.x + mg.x - 2.0f * acc[it][jt][reg], 0.f);
        const float sim = __builtin_amdgcn_exp2f(-1.4426950408889634f *
                                                 __builtin_amdgcn_sqrtf(sq));
        if (gt == __float_as_uint(mg.y)) nv += sim; else dv += sim;
      }
    }
    red[(ir * 2 + h) * 256 + tl] = make_float2(nv, dv);
  }
  __syncthreads();
  if (tid < 256) {
    float n = 0.f, d = 0.f;
    #pragma unroll
    for (int s = 0; s < 4; ++s) {
      const float2 v = red[s * 256 + tid];
      n += v.x; d += v.y;
    }
    part[(size_t)bx * Bn + brow + tid] = make_float2(n, d);
  }
}

// ---------------------------------------------------------------------------
// Kernel 3a: per-row sum over 64 image-panel partials + loss term -> block sums.
// Kernel 3b: final reduce of 32 block sums.
// ---------------------------------------------------------------------------
__global__ __launch_bounds__(256) void finalize1_kernel(
    const float2* __restrict__ part, float* __restrict__ bsum)
{
  const int i = blockIdx.x * 256 + threadIdx.x;
  float nv = 0.f, dv = 0.f;
  #pragma unroll 8
  for (int p = 0; p < 64; ++p) {
    const float2 v = part[(size_t)p * Bn + i];
    nv += v.x; dv += v.y;
  }
  float li = (nv > 0.f && dv > 0.f)
      ? (__builtin_amdgcn_logf(dv) - __builtin_amdgcn_logf(nv)) * 0.69314718055994531f
      : 0.f;
  #pragma unroll
  for (int off = 32; off >= 1; off >>= 1) li += __shfl_xor(li, off, 64);
  __shared__ float ws4[4];
  if ((threadIdx.x & 63) == 0) ws4[threadIdx.x >> 6] = li;
  __syncthreads();
  if (threadIdx.x == 0) bsum[blockIdx.x] = ws4[0] + ws4[1] + ws4[2] + ws4[3];
}

__global__ void finalize2_kernel(const float* __restrict__ bsum, float* __restrict__ out)
{
  float s = (threadIdx.x < 32) ? bsum[threadIdx.x] : 0.f;
  #pragma unroll
  for (int off = 32; off >= 1; off >>= 1) s += __shfl_xor(s, off, 64);
  if (threadIdx.x == 0) out[0] = s / (float)Bn;
}

// ---------------------------------------------------------------------------
extern "C" void kernel_launch(void* const* d_in, const int* in_sizes, int n_in,
                              void* d_out, int out_size, void* d_ws, size_t ws_size,
                              hipStream_t stream) {
  const float* T = (const float*)d_in[0];
  const float* M = (const float*)d_in[1];
  const int* groups = (const int*)d_in[2];

  char* ws = (char*)d_ws;
  uint8_t* Tq = (uint8_t*)ws;                                   // 4 MB fp8 text
  uint8_t* Mq = (uint8_t*)(ws + (size_t)Bn * Dk);               // 4 MB fp8 image
  float* tn  = (float*)(ws + (size_t)Bn * Dk * 2);              // 32 KB
  float* mn  = tn + Bn;                                         // 32 KB
  float2* part = (float2*)(mn + Bn);                            // 4 MB (64 x 8192)
  float* bsum = (float*)(part + (size_t)64 * Bn);               // 128 B

  const int smem_bytes = 2 * 16384 + 2 * 8192 + 256 * 8 + 128 * 8;  // 52224 B
  hipFuncSetAttribute((const void*)gemm_epi_kernel,
                      hipFuncAttributeMaxDynamicSharedMemorySize, smem_bytes);

  prep_kernel<<<2 * Bn, 128, 0, stream>>>(T, M, Tq, Mq, tn, mn);
  gemm_epi_kernel<<<2048, 512, smem_bytes, stream>>>(Tq, Mq, tn, mn, groups, part);
  finalize1_kernel<<<Bn / 256, 256, 0, stream>>>(part, bsum);
  finalize2_kernel<<<1, 64, 0, stream>>>(bsum, (float*)d_out);
}

// Round 10
// 76.153 us; speedup vs baseline: 2.1843x; 2.1843x over previous
//
#include <hip/hip_runtime.h>
#include <hip/hip_bf16.h>
#include <stdint.h>

#define Bn 8192
#define Dk 512
#define SCALE1 0x7F7F7F7F   // e8m0 127 (=1.0) in every byte: opsel-proof

typedef __attribute__((ext_vector_type(8))) int   int8v;
typedef __attribute__((ext_vector_type(4))) int   int4v;
typedef __attribute__((ext_vector_type(16))) float f32x16;

// async global -> LDS, 16 bytes per lane (dest = wave-uniform base + lane*16)
__device__ __forceinline__ void gload_lds16(const uint8_t* g, const uint8_t* l) {
  __builtin_amdgcn_global_load_lds(
      (const __attribute__((address_space(1))) void*)g,
      (__attribute__((address_space(3))) void*)l,
      16, 0, 0);
}

// ---------------------------------------------------------------------------
// Kernel 1: cast fp32 embeddings to fp8 e4m3 + exact fp32 row norms.
// ---------------------------------------------------------------------------
__global__ __launch_bounds__(128) void prep_kernel(
    const float* __restrict__ T, const float* __restrict__ M,
    uint8_t* __restrict__ Tq, uint8_t* __restrict__ Mq,
    float* __restrict__ tn, float* __restrict__ mn)
{
  const int bid = blockIdx.x;
  const int row = bid & (Bn - 1);
  const bool isM = bid >= Bn;
  const float* __restrict__ src = isM ? M : T;
  unsigned* __restrict__ dst = (unsigned*)(isM ? Mq : Tq);
  const int tid = threadIdx.x;

  float4 v = reinterpret_cast<const float4*>(src + (size_t)row * Dk)[tid];
  float s = v.x * v.x + v.y * v.y + v.z * v.z + v.w * v.w;
  int p = __builtin_amdgcn_cvt_pk_fp8_f32(v.x, v.y, 0, false);
  p = __builtin_amdgcn_cvt_pk_fp8_f32(v.z, v.w, p, true);
  dst[(size_t)row * 128 + tid] = (unsigned)p;

  #pragma unroll
  for (int off = 32; off >= 1; off >>= 1) s += __shfl_xor(s, off, 64);
  __shared__ float ws2[2];
  if ((tid & 63) == 0) ws2[tid >> 6] = s;
  __syncthreads();
  if (tid == 0) (isM ? mn : tn)[row] = ws2[0] + ws2[1];
}

// ---------------------------------------------------------------------------
// Kernel 2: R8 structure verbatim (256x256 MX-fp8 tile, BK=64, ring-4,
// barrier every 2 steps, counted vmcnt(8), by-fast XCD swizzle) with ONE
// change: conflict-free 32-row-group LDS permutation instead of XOR pairing.
// Chunk (row r, 16B-slot s) -> linear chunk idx (r>>5)*128 + s*32 + (r&31),
// applied on the per-lane GLOBAL source (LDS dest stays linear per wave).
// Fragment read per wave = two contiguous 512 B blocks (lo +h*1024+l31*16,
// hi +512) -> uniform 8 dwords/bank, the measured-zero-conflict class.
// ---------------------------------------------------------------------------
__global__ __launch_bounds__(512, 2) void gemm_epi_kernel(
    const uint8_t* __restrict__ Tq, const uint8_t* __restrict__ Mq,
    const float* __restrict__ tn, const float* __restrict__ mn,
    const int* __restrict__ groups,
    float2* __restrict__ part)
{
  extern __shared__ char smem[];
  uint8_t* As8 = (uint8_t*)smem;           // text tiles: 4 bufs x 256x64 fp8
  uint8_t* Bs8 = As8 + 4 * 16384;          // image tiles: 4 bufs
  float2* tg_s = (float2*)(Bs8 + 4 * 16384);  // 256 (text norm, group bits)
  float2* mg_s = tg_s + 256;                  // 256 (image norm, group bits)

  const int tid = threadIdx.x;
  const int wave = tid >> 6;
  const int lane = tid & 63;
  const int l31 = lane & 31, h = lane >> 5;

  // XCD-compact swizzle (R8): by FAST within XCD -> each image panel reused
  // by 4 consecutive blocks; text slice (4x256 rows) stays L2-resident.
  const int bid = blockIdx.x;
  const int xcd = bid & 7, lidx = bid >> 3;
  const int by = xcd * 4 + (lidx & 3);
  const int bx = lidx >> 2;
  const int brow = by * 256;   // text rows
  const int bcol = bx * 256;   // image rows

  const int ir = wave >> 2;    // image half: rows ir*128 .. +128
  const int tc = wave & 3;     // text quarter: cols tc*64 .. +64

  if (tid < 256) {
    tg_s[tid] = make_float2(tn[brow + tid], __uint_as_float((unsigned)groups[brow + tid]));
  } else {
    const int t = tid - 256;
    mg_s[t] = make_float2(mn[bcol + t], __uint_as_float((unsigned)groups[bcol + t]));
  }

  // staging: K-tile = 256 rows x 64 B = 1024 chunks of 16 B per operand;
  // 512 threads -> 2 chunks per thread per operand. Permuted source (rule
  // #21): linear LDS chunk L holds row (L>>7)*32+(L&31), slot (L>>5)&3.
  int ldsoff[2];
  unsigned goffT[2], goffM[2];   // byte offsets
  #pragma unroll
  for (int i = 0; i < 2; ++i) {
    const int c = i * 512 + tid;
    const int r = (c >> 7) * 32 + (c & 31);
    const int s = (c >> 5) & 3;
    goffT[i] = (unsigned)(brow + r) * Dk + s * 16;
    goffM[i] = (unsigned)(bcol + r) * Dk + s * 16;
    ldsoff[i] = (i * 512 + wave * 64) * 16;   // wave-uniform byte base
  }

  auto stage = [&](int t, int buf) {
    const int k0 = t * 64;   // byte offset along the row
    #pragma unroll
    for (int i = 0; i < 2; ++i) {
      gload_lds16(Tq + goffT[i] + k0, As8 + buf * 16384 + ldsoff[i]);
      gload_lds16(Mq + goffM[i] + k0, Bs8 + buf * 16384 + ldsoff[i]);
    }
  };

  // fragment read offsets (kt-independent): lane (l31,h) of frag at row
  // group g reads lo = g*2048 + h*1024 + l31*16 (slot 2h), hi = +512 (2h+1).
  int toffB[2], moffB[4];
  #pragma unroll
  for (int jt = 0; jt < 2; ++jt)
    toffB[jt] = (tc * 2 + jt) * 2048 + h * 1024 + l31 * 16;
  #pragma unroll
  for (int it = 0; it < 4; ++it)
    moffB[it] = (ir * 4 + it) * 2048 + h * 1024 + l31 * 16;

  f32x16 acc[4][2];
  #pragma unroll
  for (int it = 0; it < 4; ++it)
    #pragma unroll
    for (int jt = 0; jt < 2; ++jt)
      #pragma unroll
      for (int e = 0; e < 16; ++e)
        acc[it][jt][e] = 0.f;

  // prologue: tiles 0,1 staged; tile 0 resident before first reads
  stage(0, 0); stage(1, 1);
  asm volatile("s_waitcnt vmcnt(4)" ::: "memory");
  __builtin_amdgcn_s_barrier();
  int kt = 0;

#define STEP(BUF, DO_STAGE, DO_BAR, VMC)                                       \
  do {                                                                         \
    if (DO_BAR) __builtin_amdgcn_s_barrier();                                  \
    if (DO_STAGE) stage(kt + 2, ((BUF) + 2) & 3);                              \
    asm volatile("s_waitcnt vmcnt(" #VMC ")" ::: "memory");                    \
    int8v tf[2], mf[4];                                                        \
    _Pragma("unroll")                                                          \
    for (int jt = 0; jt < 2; ++jt) {                                           \
      int4v lo = *(const int4v*)(As8 + (BUF) * 16384 + toffB[jt]);             \
      int4v hi = *(const int4v*)(As8 + (BUF) * 16384 + toffB[jt] + 512);       \
      tf[jt] = __builtin_shufflevector(lo, hi, 0, 1, 2, 3, 4, 5, 6, 7);        \
    }                                                                          \
    _Pragma("unroll")                                                          \
    for (int it = 0; it < 4; ++it) {                                           \
      int4v lo = *(const int4v*)(Bs8 + (BUF) * 16384 + moffB[it]);             \
      int4v hi = *(const int4v*)(Bs8 + (BUF) * 16384 + moffB[it] + 512);       \
      mf[it] = __builtin_shufflevector(lo, hi, 0, 1, 2, 3, 4, 5, 6, 7);        \
    }                                                                          \
    __builtin_amdgcn_s_setprio(1);                                             \
    _Pragma("unroll")                                                          \
    for (int it = 0; it < 4; ++it)                                             \
      _Pragma("unroll")                                                        \
      for (int jt = 0; jt < 2; ++jt)                                           \
        acc[it][jt] = __builtin_amdgcn_mfma_scale_f32_32x32x64_f8f6f4(         \
            mf[it], tf[jt], acc[it][jt], 0, 0, 0, SCALE1, 0, SCALE1);          \
    __builtin_amdgcn_s_setprio(0);                                             \
    ++kt;                                                                      \
  } while (0)

  STEP(0, true,  true,  8);   // kt=0: stages tile 2
  STEP(1, true,  false, 8);   // kt=1: tile 3
  STEP(2, true,  true,  8);   // kt=2: tile 4
  STEP(3, true,  false, 8);   // kt=3: tile 5
  STEP(0, true,  true,  8);   // kt=4: tile 6
  STEP(1, true,  false, 8);   // kt=5: tile 7 (last)
  STEP(2, false, true,  4);   // kt=6: tiles 6,7 outstanding -> wait to 4
  STEP(3, false, false, 0);   // kt=7: drain
#undef STEP

  // ---- fused epilogue (no atomics) ----
  // acc[it][jt][reg] on lane (l31,h) = dot(image[bcol+ir*128+it*32+crow],
  //                                        text [brow+tc*64+jt*32+l31])
  // with crow = (reg&3) + 8*(reg>>2) + 4*h.
  float2* red = reinterpret_cast<float2*>(As8);   // 8 KB alias on buf0 (dead)

  float nv[2] = {0.f, 0.f}, dv[2] = {0.f, 0.f};
  const int tl0 = tc * 64 + l31;
  const float2 tgA = tg_s[tl0];
  const float2 tgB = tg_s[tl0 + 32];
  #pragma unroll
  for (int it = 0; it < 4; ++it) {
    #pragma unroll
    for (int reg = 0; reg < 16; ++reg) {
      const int crow = (reg & 3) + 8 * (reg >> 2) + 4 * h;
      const float2 mg = mg_s[ir * 128 + it * 32 + crow];
      const unsigned gm = __float_as_uint(mg.y);
      {
        const float sq = fmaxf(tgA.x + mg.x - 2.0f * acc[it][0][reg], 0.f);
        const float sim = __builtin_amdgcn_exp2f(-1.4426950408889634f *
                                                 __builtin_amdgcn_sqrtf(sq));
        if (__float_as_uint(tgA.y) == gm) nv[0] += sim; else dv[0] += sim;
      }
      {
        const float sq = fmaxf(tgB.x + mg.x - 2.0f * acc[it][1][reg], 0.f);
        const float sim = __builtin_amdgcn_exp2f(-1.4426950408889634f *
                                                 __builtin_amdgcn_sqrtf(sq));
        if (__float_as_uint(tgB.y) == gm) nv[1] += sim; else dv[1] += sim;
      }
    }
  }
  __syncthreads();   // all waves done with LDS tile bufs before red alias
  const int slot = ir * 2 + h;
  red[slot * 256 + tl0]      = make_float2(nv[0], dv[0]);
  red[slot * 256 + tl0 + 32] = make_float2(nv[1], dv[1]);
  __syncthreads();
  if (tid < 256) {
    float n = 0.f, d = 0.f;
    #pragma unroll
    for (int s = 0; s < 4; ++s) {
      const float2 v = red[s * 256 + tid];
      n += v.x; d += v.y;
    }
    part[(size_t)bx * Bn + brow + tid] = make_float2(n, d);
  }
}

// ---------------------------------------------------------------------------
// Kernel 3a: per-row sum over 32 image-panel partials + loss term -> block sums.
// Kernel 3b: final reduce of 32 block sums.
// ---------------------------------------------------------------------------
__global__ __launch_bounds__(256) void finalize1_kernel(
    const float2* __restrict__ part, float* __restrict__ bsum)
{
  const int i = blockIdx.x * 256 + threadIdx.x;
  float nv = 0.f, dv = 0.f;
  #pragma unroll 8
  for (int p = 0; p < 32; ++p) {
    const float2 v = part[(size_t)p * Bn + i];
    nv += v.x; dv += v.y;
  }
  float li = (nv > 0.f && dv > 0.f)
      ? (__builtin_amdgcn_logf(dv) - __builtin_amdgcn_logf(nv)) * 0.69314718055994531f
      : 0.f;
  #pragma unroll
  for (int off = 32; off >= 1; off >>= 1) li += __shfl_xor(li, off, 64);
  __shared__ float ws4[4];
  if ((threadIdx.x & 63) == 0) ws4[threadIdx.x >> 6] = li;
  __syncthreads();
  if (threadIdx.x == 0) bsum[blockIdx.x] = ws4[0] + ws4[1] + ws4[2] + ws4[3];
}

__global__ void finalize2_kernel(const float* __restrict__ bsum, float* __restrict__ out)
{
  float s = (threadIdx.x < 32) ? bsum[threadIdx.x] : 0.f;
  #pragma unroll
  for (int off = 32; off >= 1; off >>= 1) s += __shfl_xor(s, off, 64);
  if (threadIdx.x == 0) out[0] = s / (float)Bn;
}

// ---------------------------------------------------------------------------
extern "C" void kernel_launch(void* const* d_in, const int* in_sizes, int n_in,
                              void* d_out, int out_size, void* d_ws, size_t ws_size,
                              hipStream_t stream) {
  const float* T = (const float*)d_in[0];
  const float* M = (const float*)d_in[1];
  const int* groups = (const int*)d_in[2];

  char* ws = (char*)d_ws;
  uint8_t* Tq = (uint8_t*)ws;                                   // 4 MB fp8 text
  uint8_t* Mq = (uint8_t*)(ws + (size_t)Bn * Dk);               // 4 MB fp8 image
  float* tn  = (float*)(ws + (size_t)Bn * Dk * 2);              // 32 KB
  float* mn  = tn + Bn;                                         // 32 KB
  float2* part = (float2*)(mn + Bn);                            // 2 MB (32 x 8192)
  float* bsum = (float*)(part + (size_t)32 * Bn);               // 128 B

  const int smem_bytes = 8 * 16384 + 512 * 8;   // 128 KB tiles + 4 KB norms
  hipFuncSetAttribute((const void*)gemm_epi_kernel,
                      hipFuncAttributeMaxDynamicSharedMemorySize, smem_bytes);

  prep_kernel<<<2 * Bn, 128, 0, stream>>>(T, M, Tq, Mq, tn, mn);
  gemm_epi_kernel<<<1024, 512, smem_bytes, stream>>>(Tq, Mq, tn, mn, groups, part);
  finalize1_kernel<<<Bn / 256, 256, 0, stream>>>(part, bsum);
  finalize2_kernel<<<1, 64, 0, stream>>>(bsum, (float*)d_out);
}

// Round 11
// 64.875 us; speedup vs baseline: 2.5641x; 1.1738x over previous
//
#include <hip/hip_runtime.h>
#include <hip/hip_bf16.h>
#include <stdint.h>

#define Bn 8192
#define Dk 512
#define SCALE1 0x7F7F7F7F   // e8m0 127 (=1.0) in every byte: opsel-proof

typedef __attribute__((ext_vector_type(8))) int   int8v;
typedef __attribute__((ext_vector_type(4))) int   int4v;
typedef __attribute__((ext_vector_type(16))) float f32x16;

// async global -> LDS, 16 bytes per lane (dest = wave-uniform base + lane*16)
__device__ __forceinline__ void gload_lds16(const uint8_t* g, const uint8_t* l) {
  __builtin_amdgcn_global_load_lds(
      (const __attribute__((address_space(1))) void*)g,
      (__attribute__((address_space(3))) void*)l,
      16, 0, 0);
}

// ---------------------------------------------------------------------------
// Kernel 1: cast fp32 embeddings to fp8 e4m3 + exact fp32 row norms.
// ---------------------------------------------------------------------------
__global__ __launch_bounds__(128) void prep_kernel(
    const float* __restrict__ T, const float* __restrict__ M,
    uint8_t* __restrict__ Tq, uint8_t* __restrict__ Mq,
    float* __restrict__ tn, float* __restrict__ mn)
{
  const int bid = blockIdx.x;
  const int row = bid & (Bn - 1);
  const bool isM = bid >= Bn;
  const float* __restrict__ src = isM ? M : T;
  unsigned* __restrict__ dst = (unsigned*)(isM ? Mq : Tq);
  const int tid = threadIdx.x;

  float4 v = reinterpret_cast<const float4*>(src + (size_t)row * Dk)[tid];
  float s = v.x * v.x + v.y * v.y + v.z * v.z + v.w * v.w;
  int p = __builtin_amdgcn_cvt_pk_fp8_f32(v.x, v.y, 0, false);
  p = __builtin_amdgcn_cvt_pk_fp8_f32(v.z, v.w, p, true);
  dst[(size_t)row * 128 + tid] = (unsigned)p;

  #pragma unroll
  for (int off = 32; off >= 1; off >>= 1) s += __shfl_xor(s, off, 64);
  __shared__ float ws2[2];
  if ((tid & 63) == 0) ws2[tid >> 6] = s;
  __syncthreads();
  if (tid == 0) (isM ? mn : tn)[row] = ws2[0] + ws2[1];
}

// ---------------------------------------------------------------------------
// Kernel 2: 256x128-tile MX-fp8 GEMM (scale=1.0), BK=64. R8's verbatim XOR
// LDS layout + 64B-segment staging source + by-fast XCD swizzle + 1-barrier
// counted-vmcnt cadence; ONLY change vs R8: block geometry for occupancy.
// 8 waves = 4 text-quarters x 2 image-halves, wave tile 64x64, acc = 64 f32
// -> ~64 VGPR + 64 AGPR = 128 combined = 4 waves/SIMD = 2 blocks/CU.
// LDS ring-3 (3 x 24 KB + norms = 76.8 KB <= 80 KB/block at 2 blocks/CU).
// Two independent blocks/CU overlap one block's LDS/stage/epilogue phases
// with the other's MFMA -- the overlap intra-block scheduling couldn't make.
// Ring safety: stage(kt+2) (after barrier kt) overwrites buf[(kt+2)%3] =
// buf[kt-1]; every wave's buf[kt-1] ds_reads were consumed by its step-kt-1
// MFMAs before it reached barrier kt. vmcnt(6) retires tile kt (3 loads per
// stage, 2 stages in flight; in-order retirement m135).
// ---------------------------------------------------------------------------
__global__ __launch_bounds__(512, 4) void gemm_epi_kernel(
    const uint8_t* __restrict__ Tq, const uint8_t* __restrict__ Mq,
    const float* __restrict__ tn, const float* __restrict__ mn,
    const int* __restrict__ groups,
    float2* __restrict__ part)
{
  extern __shared__ char smem[];
  uint8_t* As8 = (uint8_t*)smem;              // text: 3 bufs x 256x64 fp8
  uint8_t* Bs8 = As8 + 3 * 16384;             // image: 3 bufs x 128x64 fp8
  float2* tg_s = (float2*)(Bs8 + 3 * 8192);   // 256 (text norm, group bits)
  float2* mg_s = tg_s + 256;                  // 128 (image norm, group bits)

  const int tid = threadIdx.x;
  const int wave = tid >> 6;
  const int lane = tid & 63;
  const int l31 = lane & 31, h = lane >> 5;

  // XCD-compact swizzle, by FAST within XCD (R8 reuse axis):
  // 2048 blocks = 8 XCDs x (4 by x 64 bx)
  const int bid = blockIdx.x;
  const int xcd = bid & 7, lidx = bid >> 3;
  const int by = xcd * 4 + (lidx & 3);   // 0..31 text panel (256 rows)
  const int bx = lidx >> 2;              // 0..63 image panel (128 rows)
  const int brow = by * 256;
  const int bcol = bx * 128;

  const int tc = wave & 3;     // text quarter: rows tc*64 .. +64
  const int ir = wave >> 2;    // image half:  rows ir*64 .. +64

  if (tid < 256) {
    tg_s[tid] = make_float2(tn[brow + tid], __uint_as_float((unsigned)groups[brow + tid]));
  } else if (tid < 384) {
    const int t = tid - 256;
    mg_s[t] = make_float2(mn[bcol + t], __uint_as_float((unsigned)groups[bcol + t]));
  }

  // staging (R8 scheme): text K-tile = 256 rows x 64 B = 1024 chunks (2 per
  // thread); image = 128 rows = 512 chunks (1 per thread). XOR-swizzled
  // source slot sc = (c&3) ^ ((row>>1)&3) -> each row's full 64 B covered
  // (permuted within the row) => 64 B global segments. LDS dest linear.
  int ldsT[2], ldsM;
  unsigned goffT[2], goffM;
  #pragma unroll
  for (int i = 0; i < 2; ++i) {
    const int c = i * 512 + tid;
    const int r = c >> 2;
    const int sc = (c & 3) ^ ((r >> 1) & 3);
    goffT[i] = (unsigned)(brow + r) * Dk + sc * 16;
    ldsT[i] = (i * 512 + wave * 64) * 16;
  }
  {
    const int c = tid;
    const int r = c >> 2;
    const int sc = (c & 3) ^ ((r >> 1) & 3);
    goffM = (unsigned)(bcol + r) * Dk + sc * 16;
    ldsM = wave * 64 * 16;
  }

  auto stage = [&](int t, int buf) {
    const int k0 = t * 64;
    gload_lds16(Tq + goffT[0] + k0, As8 + buf * 16384 + ldsT[0]);
    gload_lds16(Tq + goffT[1] + k0, As8 + buf * 16384 + ldsT[1]);
    gload_lds16(Mq + goffM + k0, Bs8 + buf * 8192 + ldsM);
  };

  // fragment read offsets (R8 XOR pairing, kt-independent): lane (l31,h)
  // reads source slots {2h, 2h+1} of row r at stored idx (2h)^f and ^1.
  int toffB[2], moffB[2];
  #pragma unroll
  for (int jt = 0; jt < 2; ++jt) {
    const int r = tc * 64 + jt * 32 + l31;
    toffB[jt] = r * 64 + (((h << 1) ^ ((r >> 1) & 3)) << 4);
  }
  #pragma unroll
  for (int it = 0; it < 2; ++it) {
    const int r = ir * 64 + it * 32 + l31;
    moffB[it] = r * 64 + (((h << 1) ^ ((r >> 1) & 3)) << 4);
  }

  f32x16 acc[2][2];
  #pragma unroll
  for (int it = 0; it < 2; ++it)
    #pragma unroll
    for (int jt = 0; jt < 2; ++jt)
      #pragma unroll
      for (int e = 0; e < 16; ++e)
        acc[it][jt][e] = 0.f;

  // prologue: tiles 0,1 staged; tile 0 resident before first reads
  stage(0, 0); stage(1, 1);
  asm volatile("s_waitcnt vmcnt(3)" ::: "memory");
  __builtin_amdgcn_s_barrier();
  int kt = 0;

#define STEP(BUF, DO_STAGE, VMC)                                               \
  do {                                                                         \
    __builtin_amdgcn_s_barrier();                                              \
    if (DO_STAGE) stage(kt + 2, ((BUF) + 2) % 3);                              \
    asm volatile("s_waitcnt vmcnt(" #VMC ")" ::: "memory");                    \
    int8v tf[2], mf[2];                                                        \
    _Pragma("unroll")                                                          \
    for (int jt = 0; jt < 2; ++jt) {                                           \
      int4v lo = *(const int4v*)(As8 + (BUF) * 16384 + toffB[jt]);             \
      int4v hi = *(const int4v*)(As8 + (BUF) * 16384 + (toffB[jt] ^ 16));      \
      tf[jt] = __builtin_shufflevector(lo, hi, 0, 1, 2, 3, 4, 5, 6, 7);        \
    }                                                                          \
    _Pragma("unroll")                                                          \
    for (int it = 0; it < 2; ++it) {                                           \
      int4v lo = *(const int4v*)(Bs8 + (BUF) * 8192 + moffB[it]);              \
      int4v hi = *(const int4v*)(Bs8 + (BUF) * 8192 + (moffB[it] ^ 16));       \
      mf[it] = __builtin_shufflevector(lo, hi, 0, 1, 2, 3, 4, 5, 6, 7);        \
    }                                                                          \
    __builtin_amdgcn_s_setprio(1);                                             \
    _Pragma("unroll")                                                          \
    for (int it = 0; it < 2; ++it)                                             \
      _Pragma("unroll")                                                        \
      for (int jt = 0; jt < 2; ++jt)                                           \
        acc[it][jt] = __builtin_amdgcn_mfma_scale_f32_32x32x64_f8f6f4(         \
            mf[it], tf[jt], acc[it][jt], 0, 0, 0, SCALE1, 0, SCALE1);          \
    __builtin_amdgcn_s_setprio(0);                                             \
    ++kt;                                                                      \
  } while (0)

  STEP(0, true,  6);   // kt=0: stages tile 2
  STEP(1, true,  6);   // kt=1: tile 3
  STEP(2, true,  6);   // kt=2: tile 4
  STEP(0, true,  6);   // kt=3: tile 5
  STEP(1, true,  6);   // kt=4: tile 6
  STEP(2, true,  6);   // kt=5: tile 7 (last)
  STEP(0, false, 3);   // kt=6: tile 7's 3 loads outstanding -> wait to 3
  STEP(1, false, 0);   // kt=7: drain
#undef STEP

  // ---- fused epilogue (no atomics) ----
  // acc[it][jt][reg] on lane (l31,h) = dot(image[bcol+ir*64+it*32+crow],
  //                                        text [brow+tc*64+jt*32+l31])
  // with crow = (reg&3) + 8*(reg>>2) + 4*h.
  float2* red = reinterpret_cast<float2*>(As8);   // 16 KB alias on buf0 (dead)

  float nv[2] = {0.f, 0.f}, dv[2] = {0.f, 0.f};
  const int tlA = tc * 64 + l31;          // jt = 0
  const int tlB = tlA + 32;               // jt = 1
  const float2 tgA = tg_s[tlA];
  const float2 tgB = tg_s[tlB];
  #pragma unroll
  for (int it = 0; it < 2; ++it) {
    #pragma unroll
    for (int reg = 0; reg < 16; ++reg) {
      const int crow = (reg & 3) + 8 * (reg >> 2) + 4 * h;
      const float2 mg = mg_s[ir * 64 + it * 32 + crow];
      const unsigned gm = __float_as_uint(mg.y);
      {
        const float sq = fmaxf(tgA.x + mg.x - 2.0f * acc[it][0][reg], 0.f);
        const float sim = __builtin_amdgcn_exp2f(-1.4426950408889634f *
                                                 __builtin_amdgcn_sqrtf(sq));
        if (__float_as_uint(tgA.y) == gm) nv[0] += sim; else dv[0] += sim;
      }
      {
        const float sq = fmaxf(tgB.x + mg.x - 2.0f * acc[it][1][reg], 0.f);
        const float sim = __builtin_amdgcn_exp2f(-1.4426950408889634f *
                                                 __builtin_amdgcn_sqrtf(sq));
        if (__float_as_uint(tgB.y) == gm) nv[1] += sim; else dv[1] += sim;
      }
    }
  }
  __syncthreads();   // all waves done with LDS tile bufs before red alias
  const int slot = ir * 2 + h;
  red[slot * 256 + tlA] = make_float2(nv[0], dv[0]);
  red[slot * 256 + tlB] = make_float2(nv[1], dv[1]);
  __syncthreads();
  if (tid < 256) {
    float n = 0.f, d = 0.f;
    #pragma unroll
    for (int s = 0; s < 4; ++s) {
      const float2 v = red[s * 256 + tid];
      n += v.x; d += v.y;
    }
    part[(size_t)bx * Bn + brow + tid] = make_float2(n, d);
  }
}

// ---------------------------------------------------------------------------
// Kernel 3a: per-row sum over 64 image-panel partials + loss term -> block sums.
// Kernel 3b: final reduce of 32 block sums.
// ---------------------------------------------------------------------------
__global__ __launch_bounds__(256) void finalize1_kernel(
    const float2* __restrict__ part, float* __restrict__ bsum)
{
  const int i = blockIdx.x * 256 + threadIdx.x;
  float nv = 0.f, dv = 0.f;
  #pragma unroll 8
  for (int p = 0; p < 64; ++p) {
    const float2 v = part[(size_t)p * Bn + i];
    nv += v.x; dv += v.y;
  }
  float li = (nv > 0.f && dv > 0.f)
      ? (__builtin_amdgcn_logf(dv) - __builtin_amdgcn_logf(nv)) * 0.69314718055994531f
      : 0.f;
  #pragma unroll
  for (int off = 32; off >= 1; off >>= 1) li += __shfl_xor(li, off, 64);
  __shared__ float ws4[4];
  if ((threadIdx.x & 63) == 0) ws4[threadIdx.x >> 6] = li;
  __syncthreads();
  if (threadIdx.x == 0) bsum[blockIdx.x] = ws4[0] + ws4[1] + ws4[2] + ws4[3];
}

__global__ void finalize2_kernel(const float* __restrict__ bsum, float* __restrict__ out)
{
  float s = (threadIdx.x < 32) ? bsum[threadIdx.x] : 0.f;
  #pragma unroll
  for (int off = 32; off >= 1; off >>= 1) s += __shfl_xor(s, off, 64);
  if (threadIdx.x == 0) out[0] = s / (float)Bn;
}

// ---------------------------------------------------------------------------
extern "C" void kernel_launch(void* const* d_in, const int* in_sizes, int n_in,
                              void* d_out, int out_size, void* d_ws, size_t ws_size,
                              hipStream_t stream) {
  const float* T = (const float*)d_in[0];
  const float* M = (const float*)d_in[1];
  const int* groups = (const int*)d_in[2];

  char* ws = (char*)d_ws;
  uint8_t* Tq = (uint8_t*)ws;                                   // 4 MB fp8 text
  uint8_t* Mq = (uint8_t*)(ws + (size_t)Bn * Dk);               // 4 MB fp8 image
  float* tn  = (float*)(ws + (size_t)Bn * Dk * 2);              // 32 KB
  float* mn  = tn + Bn;                                         // 32 KB
  float2* part = (float2*)(mn + Bn);                            // 4 MB (64 x 8192)
  float* bsum = (float*)(part + (size_t)64 * Bn);               // 128 B

  const int smem_bytes = 3 * 16384 + 3 * 8192 + 256 * 8 + 128 * 8;  // 76800 B
  hipFuncSetAttribute((const void*)gemm_epi_kernel,
                      hipFuncAttributeMaxDynamicSharedMemorySize, smem_bytes);

  prep_kernel<<<2 * Bn, 128, 0, stream>>>(T, M, Tq, Mq, tn, mn);
  gemm_epi_kernel<<<2048, 512, smem_bytes, stream>>>(Tq, Mq, tn, mn, groups, part);
  finalize1_kernel<<<Bn / 256, 256, 0, stream>>>(part, bsum);
  finalize2_kernel<<<1, 64, 0, stream>>>(bsum, (float*)d_out);
}

// Round 12
// 61.834 us; speedup vs baseline: 2.6901x; 1.0492x over previous
//
#include <hip/hip_runtime.h>
#include <hip/hip_bf16.h>
#include <stdint.h>

#define Bn 8192
#define Dk 512
#define SCALE1 0x7F7F7F7F   // e8m0 127 (=1.0) in every byte: opsel-proof

typedef __attribute__((ext_vector_type(8))) int   int8v;
typedef __attribute__((ext_vector_type(4))) int   int4v;
typedef __attribute__((ext_vector_type(16))) float f32x16;

// async global -> LDS, 16 bytes per lane (dest = wave-uniform base + lane*16)
__device__ __forceinline__ void gload_lds16(const uint8_t* g, const uint8_t* l) {
  __builtin_amdgcn_global_load_lds(
      (const __attribute__((address_space(1))) void*)g,
      (__attribute__((address_space(3))) void*)l,
      16, 0, 0);
}

// ---------------------------------------------------------------------------
// Kernel 1: cast fp32 -> fp8 e4m3, writing the TRANSPOSED panel layout the
// GEMM wants: text  [32 panels][8 kt][8 g][4 s][32 r][16B]  (131072 B/panel)
//            image [64 panels][8 kt][4 g][4 s][32 r][16B]  ( 65536 B/panel)
// so GEMM staging is a linear copy and LDS frag reads are conflict-free.
// One block = 32 consecutive rows; 16 KB LDS transpose bounce; exact fp32
// row norms via LDS partials. All global reads/writes coalesced.
// ---------------------------------------------------------------------------
__global__ __launch_bounds__(256) void prep_kernel(
    const float* __restrict__ T, const float* __restrict__ M,
    uint8_t* __restrict__ Tq, uint8_t* __restrict__ Mq,
    float* __restrict__ tn, float* __restrict__ mn)
{
  __shared__ uint32_t lds[4096];     // 16 KB transposed fp8
  __shared__ float pn[8][33];        // per-(chunk,row) norm partials

  const int b = blockIdx.x;
  const bool isM = b >= 256;
  const int pb = b & 255;            // 32-row group index within matrix
  const int rbase = pb * 32;
  const float* __restrict__ src = isM ? M : T;
  uint8_t* __restrict__ dstq = isM ? Mq : Tq;
  float* __restrict__ nrm = isM ? mn : tn;

  const int t = threadIdx.x;
  const int c8 = t >> 5;             // which 64-float chunk of the row (= kt)
  const int r = t & 31;              // row within the 32-row group

  const float4* rowp = (const float4*)(src + (size_t)(rbase + r) * Dk) + c8 * 16;
  float s = 0.f;
  #pragma unroll
  for (int sl = 0; sl < 4; ++sl) {
    uint32_t d[4];
    #pragma unroll
    for (int j = 0; j < 4; ++j) {
      const float4 v = rowp[sl * 4 + j];
      s += v.x * v.x + v.y * v.y + v.z * v.z + v.w * v.w;
      int p = __builtin_amdgcn_cvt_pk_fp8_f32(v.x, v.y, 0, false);
      p = __builtin_amdgcn_cvt_pk_fp8_f32(v.z, v.w, p, true);
      d[j] = (uint32_t)p;
    }
    #pragma unroll
    for (int j = 0; j < 4; ++j)
      lds[c8 * 512 + sl * 128 + r * 4 + j] = d[j];
  }
  pn[c8][r] = s;
  __syncthreads();

  if (t < 32) {
    float a = 0.f;
    #pragma unroll
    for (int k = 0; k < 8; ++k) a += pn[k][t];
    nrm[rbase + t] = a;
  }

  // copy out: thread t moves 64 B; LDS within-kt order == output within-kt order
  const int kt = t >> 5;
  const int off = (t & 31) * 64;
  uint8_t* dst;
  if (!isM) {
    const int by = rbase >> 8;            // 256-row panels
    const int g = (rbase & 255) >> 5;     // 32-row group within panel
    dst = dstq + (size_t)by * 131072 + (size_t)kt * 16384 + g * 2048 + off;
  } else {
    const int bx = rbase >> 7;            // 128-row panels
    const int g = (rbase & 127) >> 5;
    dst = dstq + (size_t)bx * 65536 + (size_t)kt * 8192 + g * 2048 + off;
  }
  const uint32_t* sp = lds + t * 16;
  #pragma unroll
  for (int j = 0; j < 4; ++j)
    *(int4v*)(dst + j * 16) = *(const int4v*)(sp + j * 4);
}

// ---------------------------------------------------------------------------
// Kernel 2: 256x128-tile MX-fp8 GEMM (scale=1.0), BK=64, ring-3, vmcnt(6),
// R11 geometry (8 waves = 4 tc x 2 ir, 64x64 wave tile, 2 blocks/CU) with
// pre-transposed source: staging = linear 16 KB panel copy (1 KB contiguous
// per wave), frag reads = contiguous 512 B per half-wave (zero-conflict
// class, R10-verified). Fused atomic-free epilogue unchanged.
// ---------------------------------------------------------------------------
__global__ __launch_bounds__(512, 4) void gemm_epi_kernel(
    const uint8_t* __restrict__ Tq, const uint8_t* __restrict__ Mq,
    const float* __restrict__ tn, const float* __restrict__ mn,
    const int* __restrict__ groups,
    float2* __restrict__ part)
{
  extern __shared__ char smem[];
  uint8_t* As8 = (uint8_t*)smem;              // text: 3 bufs x 16 KB
  uint8_t* Bs8 = As8 + 3 * 16384;             // image: 3 bufs x 8 KB
  float2* tg_s = (float2*)(Bs8 + 3 * 8192);   // 256 (text norm, group bits)
  float2* mg_s = tg_s + 256;                  // 128 (image norm, group bits)

  const int tid = threadIdx.x;
  const int wave = tid >> 6;
  const int lane = tid & 63;
  const int l31 = lane & 31, h = lane >> 5;

  // XCD-compact swizzle, by FAST within XCD (R8/R11 reuse axis)
  const int bid = blockIdx.x;
  const int xcd = bid & 7, lidx = bid >> 3;
  const int by = xcd * 4 + (lidx & 3);   // 0..31 text panel (256 rows)
  const int bx = lidx >> 2;              // 0..63 image panel (128 rows)
  const int brow = by * 256;
  const int bcol = bx * 128;

  const int tc = wave & 3;     // text quarter: rows tc*64 .. +64
  const int ir = wave >> 2;    // image half:  rows ir*64 .. +64

  if (tid < 256) {
    tg_s[tid] = make_float2(tn[brow + tid], __uint_as_float((unsigned)groups[brow + tid]));
  } else if (tid < 384) {
    const int t = tid - 256;
    mg_s[t] = make_float2(mn[bcol + t], __uint_as_float((unsigned)groups[bcol + t]));
  }

  // staging: linear panel copy (source pre-transposed by prep)
  const uint8_t* Tpan = Tq + (size_t)by * 131072;
  const uint8_t* Mpan = Mq + (size_t)bx * 65536;
  int ldsT[2];
  unsigned goffT[2];
  #pragma unroll
  for (int i = 0; i < 2; ++i) {
    goffT[i] = (unsigned)(i * 512 + tid) * 16;
    ldsT[i] = (i * 512 + wave * 64) * 16;
  }
  const unsigned goffM = (unsigned)tid * 16;
  const int ldsM = wave * 64 * 16;

  auto stage = [&](int t, int buf) {
    gload_lds16(Tpan + (unsigned)t * 16384 + goffT[0], As8 + buf * 16384 + ldsT[0]);
    gload_lds16(Tpan + (unsigned)t * 16384 + goffT[1], As8 + buf * 16384 + ldsT[1]);
    gload_lds16(Mpan + (unsigned)t * 8192 + goffM, Bs8 + buf * 8192 + ldsM);
  };

  // fragment read offsets: contiguous 512 B per half-wave (lo slot 2h at
  // g*2048 + h*1024 + l31*16; hi slot 2h+1 at +512)
  int toffB[2], moffB[2];
  #pragma unroll
  for (int jt = 0; jt < 2; ++jt)
    toffB[jt] = (tc * 2 + jt) * 2048 + h * 1024 + l31 * 16;
  #pragma unroll
  for (int it = 0; it < 2; ++it)
    moffB[it] = (ir * 2 + it) * 2048 + h * 1024 + l31 * 16;

  f32x16 acc[2][2];
  #pragma unroll
  for (int it = 0; it < 2; ++it)
    #pragma unroll
    for (int jt = 0; jt < 2; ++jt)
      #pragma unroll
      for (int e = 0; e < 16; ++e)
        acc[it][jt][e] = 0.f;

  // prologue: tiles 0,1 staged; tile 0 resident before first reads
  stage(0, 0); stage(1, 1);
  asm volatile("s_waitcnt vmcnt(3)" ::: "memory");
  __builtin_amdgcn_s_barrier();
  int kt = 0;

#define STEP(BUF, DO_STAGE, VMC)                                               \
  do {                                                                         \
    __builtin_amdgcn_s_barrier();                                              \
    if (DO_STAGE) stage(kt + 2, ((BUF) + 2) % 3);                              \
    asm volatile("s_waitcnt vmcnt(" #VMC ")" ::: "memory");                    \
    int8v tf[2], mf[2];                                                        \
    _Pragma("unroll")                                                          \
    for (int jt = 0; jt < 2; ++jt) {                                           \
      int4v lo = *(const int4v*)(As8 + (BUF) * 16384 + toffB[jt]);             \
      int4v hi = *(const int4v*)(As8 + (BUF) * 16384 + toffB[jt] + 512);       \
      tf[jt] = __builtin_shufflevector(lo, hi, 0, 1, 2, 3, 4, 5, 6, 7);        \
    }                                                                          \
    _Pragma("unroll")                                                          \
    for (int it = 0; it < 2; ++it) {                                           \
      int4v lo = *(const int4v*)(Bs8 + (BUF) * 8192 + moffB[it]);              \
      int4v hi = *(const int4v*)(Bs8 + (BUF) * 8192 + moffB[it] + 512);        \
      mf[it] = __builtin_shufflevector(lo, hi, 0, 1, 2, 3, 4, 5, 6, 7);        \
    }                                                                          \
    __builtin_amdgcn_s_setprio(1);                                             \
    _Pragma("unroll")                                                          \
    for (int it = 0; it < 2; ++it)                                             \
      _Pragma("unroll")                                                        \
      for (int jt = 0; jt < 2; ++jt)                                           \
        acc[it][jt] = __builtin_amdgcn_mfma_scale_f32_32x32x64_f8f6f4(         \
            mf[it], tf[jt], acc[it][jt], 0, 0, 0, SCALE1, 0, SCALE1);          \
    __builtin_amdgcn_s_setprio(0);                                             \
    ++kt;                                                                      \
  } while (0)

  STEP(0, true,  6);   // kt=0: stages tile 2
  STEP(1, true,  6);   // kt=1: tile 3
  STEP(2, true,  6);   // kt=2: tile 4
  STEP(0, true,  6);   // kt=3: tile 5
  STEP(1, true,  6);   // kt=4: tile 6
  STEP(2, true,  6);   // kt=5: tile 7 (last)
  STEP(0, false, 3);   // kt=6: tile 7's 3 loads outstanding -> wait to 3
  STEP(1, false, 0);   // kt=7: drain
#undef STEP

  // ---- fused epilogue (no atomics) ----
  // acc[it][jt][reg] on lane (l31,h) = dot(image[bcol+ir*64+it*32+crow],
  //                                        text [brow+tc*64+jt*32+l31])
  // with crow = (reg&3) + 8*(reg>>2) + 4*h.
  float2* red = reinterpret_cast<float2*>(As8);   // 16 KB alias on buf0 (dead)

  float nv[2] = {0.f, 0.f}, dv[2] = {0.f, 0.f};
  const int tlA = tc * 64 + l31;          // jt = 0
  const int tlB = tlA + 32;               // jt = 1
  const float2 tgA = tg_s[tlA];
  const float2 tgB = tg_s[tlB];
  #pragma unroll
  for (int it = 0; it < 2; ++it) {
    #pragma unroll
    for (int reg = 0; reg < 16; ++reg) {
      const int crow = (reg & 3) + 8 * (reg >> 2) + 4 * h;
      const float2 mg = mg_s[ir * 64 + it * 32 + crow];
      const unsigned gm = __float_as_uint(mg.y);
      {
        const float sq = fmaxf(tgA.x + mg.x - 2.0f * acc[it][0][reg], 0.f);
        const float sim = __builtin_amdgcn_exp2f(-1.4426950408889634f *
                                                 __builtin_amdgcn_sqrtf(sq));
        if (__float_as_uint(tgA.y) == gm) nv[0] += sim; else dv[0] += sim;
      }
      {
        const float sq = fmaxf(tgB.x + mg.x - 2.0f * acc[it][1][reg], 0.f);
        const float sim = __builtin_amdgcn_exp2f(-1.4426950408889634f *
                                                 __builtin_amdgcn_sqrtf(sq));
        if (__float_as_uint(tgB.y) == gm) nv[1] += sim; else dv[1] += sim;
      }
    }
  }
  __syncthreads();   // all waves done with LDS tile bufs before red alias
  const int slot = ir * 2 + h;
  red[slot * 256 + tlA] = make_float2(nv[0], dv[0]);
  red[slot * 256 + tlB] = make_float2(nv[1], dv[1]);
  __syncthreads();
  if (tid < 256) {
    float n = 0.f, d = 0.f;
    #pragma unroll
    for (int s = 0; s < 4; ++s) {
      const float2 v = red[s * 256 + tid];
      n += v.x; d += v.y;
    }
    part[(size_t)bx * Bn + brow + tid] = make_float2(n, d);
  }
}

// ---------------------------------------------------------------------------
// Kernel 3a: per-row sum over 64 image-panel partials + loss term -> block sums.
// Kernel 3b: final reduce of 32 block sums.
// ---------------------------------------------------------------------------
__global__ __launch_bounds__(256) void finalize1_kernel(
    const float2* __restrict__ part, float* __restrict__ bsum)
{
  const int i = blockIdx.x * 256 + threadIdx.x;
  float nv = 0.f, dv = 0.f;
  #pragma unroll 8
  for (int p = 0; p < 64; ++p) {
    const float2 v = part[(size_t)p * Bn + i];
    nv += v.x; dv += v.y;
  }
  float li = (nv > 0.f && dv > 0.f)
      ? (__builtin_amdgcn_logf(dv) - __builtin_amdgcn_logf(nv)) * 0.69314718055994531f
      : 0.f;
  #pragma unroll
  for (int off = 32; off >= 1; off >>= 1) li += __shfl_xor(li, off, 64);
  __shared__ float ws4[4];
  if ((threadIdx.x & 63) == 0) ws4[threadIdx.x >> 6] = li;
  __syncthreads();
  if (threadIdx.x == 0) bsum[blockIdx.x] = ws4[0] + ws4[1] + ws4[2] + ws4[3];
}

__global__ void finalize2_kernel(const float* __restrict__ bsum, float* __restrict__ out)
{
  float s = (threadIdx.x < 32) ? bsum[threadIdx.x] : 0.f;
  #pragma unroll
  for (int off = 32; off >= 1; off >>= 1) s += __shfl_xor(s, off, 64);
  if (threadIdx.x == 0) out[0] = s / (float)Bn;
}

// ---------------------------------------------------------------------------
extern "C" void kernel_launch(void* const* d_in, const int* in_sizes, int n_in,
                              void* d_out, int out_size, void* d_ws, size_t ws_size,
                              hipStream_t stream) {
  const float* T = (const float*)d_in[0];
  const float* M = (const float*)d_in[1];
  const int* groups = (const int*)d_in[2];

  char* ws = (char*)d_ws;
  uint8_t* Tq = (uint8_t*)ws;                                   // 4 MB fp8 text (transposed)
  uint8_t* Mq = (uint8_t*)(ws + (size_t)Bn * Dk);               // 4 MB fp8 image (transposed)
  float* tn  = (float*)(ws + (size_t)Bn * Dk * 2);              // 32 KB
  float* mn  = tn + Bn;                                         // 32 KB
  float2* part = (float2*)(mn + Bn);                            // 4 MB (64 x 8192)
  float* bsum = (float*)(part + (size_t)64 * Bn);               // 128 B

  const int smem_bytes = 3 * 16384 + 3 * 8192 + 256 * 8 + 128 * 8;  // 76800 B
  hipFuncSetAttribute((const void*)gemm_epi_kernel,
                      hipFuncAttributeMaxDynamicSharedMemorySize, smem_bytes);

  prep_kernel<<<512, 256, 0, stream>>>(T, M, Tq, Mq, tn, mn);
  gemm_epi_kernel<<<2048, 512, smem_bytes, stream>>>(Tq, Mq, tn, mn, groups, part);
  finalize1_kernel<<<Bn / 256, 256, 0, stream>>>(part, bsum);
  finalize2_kernel<<<1, 64, 0, stream>>>(bsum, (float*)d_out);
}

// Round 13
// 58.377 us; speedup vs baseline: 2.8494x; 1.0592x over previous
//
#include <hip/hip_runtime.h>
#include <hip/hip_bf16.h>
#include <stdint.h>

#define Bn 8192
#define Dk 512
#define SCALE1 0x7F7F7F7F   // e8m0 127 (=1.0) in every byte: opsel-proof

typedef __attribute__((ext_vector_type(8))) int   int8v;
typedef __attribute__((ext_vector_type(4))) int   int4v;
typedef __attribute__((ext_vector_type(16))) float f32x16;

// async global -> LDS, 16 bytes per lane (dest = wave-uniform base + lane*16)
__device__ __forceinline__ void gload_lds16(const uint8_t* g, const uint8_t* l) {
  __builtin_amdgcn_global_load_lds(
      (const __attribute__((address_space(1))) void*)g,
      (__attribute__((address_space(3))) void*)l,
      16, 0, 0);
}

// branchless fp4 e2m1 encode of x*16 (RNE-style thresholds), sign+3-bit code.
// grid {0,.5,1,1.5,2,3,4,6} at scale 1 <=> |x| thresholds /16.
__device__ __forceinline__ uint32_t enc4(float x) {
  const float a = __builtin_fabsf(x);
  const uint32_t c =
      a < 0.046875f ? (a < 0.015625f ? 0u : 1u)
    : a < 0.109375f ? (a < 0.078125f ? 2u : 3u)
    : a < 0.21875f  ? (a < 0.15625f  ? 4u : 5u)
    :                 (a < 0.3125f   ? 6u : 7u);
  return c | (x < 0.f ? 8u : 0u);
}

// ---------------------------------------------------------------------------
// Kernel 1: fp32 -> fp4 e2m1 (values x16, scale folded out in GEMM epilogue),
// written directly in the transposed panel layout the GEMM stages linearly:
//   text : [32 panels][8 kt][8 g][2 h][32 r][16B]  (64 KB/panel)
//   image: [64 panels][8 kt][4 g][2 h][32 r][16B]  (32 KB/panel)
// Exact fp32 row norms via LDS partials. Block = 32 rows x 512 cols.
// ---------------------------------------------------------------------------
__global__ __launch_bounds__(256) void prep_kernel(
    const float* __restrict__ T, const float* __restrict__ M,
    uint8_t* __restrict__ Tq, uint8_t* __restrict__ Mq,
    float* __restrict__ tn, float* __restrict__ mn)
{
  __shared__ float pn[8][33];
  const int b = blockIdx.x;            // 512 blocks: 256 text + 256 image
  const bool isM = b >= 256;
  const int pb = b & 255;
  const int rbase = pb * 32;
  const float* __restrict__ src = isM ? M : T;
  float* __restrict__ nrm = isM ? mn : tn;

  const int t = threadIdx.x;
  const int kt = t >> 5;               // K-tile (64 floats)
  const int r = t & 31;                // row within 32-row group

  const float4* rowp = (const float4*)(src + (size_t)(rbase + r) * Dk) + kt * 16;
  float s = 0.f;
  uint32_t w[8];
  #pragma unroll
  for (int j = 0; j < 16; ++j) {
    const float4 v = rowp[j];
    s += v.x * v.x + v.y * v.y + v.z * v.z + v.w * v.w;
    const uint32_t quad = enc4(v.x) | (enc4(v.y) << 4) |
                          (enc4(v.z) << 8) | (enc4(v.w) << 12);
    if (j & 1) w[j >> 1] |= quad << 16; else w[j >> 1] = quad;
  }
  pn[kt][r] = s;

  uint8_t* dst;
  if (!isM) {
    const int by = pb >> 3, g = pb & 7;
    dst = Tq + (size_t)by * 65536 + kt * 8192 + g * 1024 + r * 16;
  } else {
    const int bx = pb >> 2, g = pb & 3;
    dst = Mq + (size_t)bx * 32768 + kt * 4096 + g * 1024 + r * 16;
  }
  *(int4v*)dst         = *(const int4v*)&w[0];   // h = 0 (k 0..31)
  *(int4v*)(dst + 512) = *(const int4v*)&w[4];   // h = 1 (k 32..63)

  __syncthreads();
  if (t < 32) {
    float a = 0.f;
    #pragma unroll
    for (int k = 0; k < 8; ++k) a += pn[k][t];
    nrm[rbase + t] = a;
  }
}

// ---------------------------------------------------------------------------
// Kernel 2: 256x128-tile MX-fp4 GEMM (scale=1.0, fmt=4 E2M1), BK=64, ring-3,
// counted vmcnt(4), R12 geometry (8 waves = 4 tc x 2 ir, 64x64 wave tile,
// 2 blocks/CU). Staging = linear copy (text 8 KB; image 4 KB x 2 LDS copies
// so every wave issues exactly 2 gloads/stage and image reads split banks).
// Frag read = ONE contiguous-1024B-per-wave ds_read_b128 (zero-conflict).
// dot' = 256*dot (values x16) -> sq = fma(acc, -2/256, tn+mn).
// Epilogue accumulates (nv, tot); dv = tot - nv in finalize.
// ---------------------------------------------------------------------------
__global__ __launch_bounds__(512, 4) void gemm_epi_kernel(
    const uint8_t* __restrict__ Tq, const uint8_t* __restrict__ Mq,
    const float* __restrict__ tn, const float* __restrict__ mn,
    const int* __restrict__ groups,
    float2* __restrict__ part)
{
  extern __shared__ char smem[];
  uint8_t* As8 = (uint8_t*)smem;              // text: 3 bufs x 8 KB
  uint8_t* Bs8 = As8 + 3 * 8192;              // image: 3 bufs x 8 KB (2 copies)
  float2* tg_s = (float2*)(Bs8 + 3 * 8192);   // 256 (text norm, group bits)
  float2* mg_s = tg_s + 256;                  // 128 (image norm, group bits)

  const int tid = threadIdx.x;
  const int wave = tid >> 6;
  const int lane = tid & 63;
  const int l31 = lane & 31, h = lane >> 5;

  // XCD-compact swizzle, by FAST within XCD (R8/R12 reuse axis)
  const int bid = blockIdx.x;
  const int xcd = bid & 7, lidx = bid >> 3;
  const int by = xcd * 4 + (lidx & 3);   // 0..31 text panel (256 rows)
  const int bx = lidx >> 2;              // 0..63 image panel (128 rows)
  const int brow = by * 256;
  const int bcol = bx * 128;

  const int tc = wave & 3;     // text quarter: rows tc*64 .. +64
  const int ir = wave >> 2;    // image half:  rows ir*64 .. +64

  if (tid < 256) {
    tg_s[tid] = make_float2(tn[brow + tid], __uint_as_float((unsigned)groups[brow + tid]));
  } else if (tid < 384) {
    const int t = tid - 256;
    mg_s[t] = make_float2(mn[bcol + t], __uint_as_float((unsigned)groups[bcol + t]));
  }

  // staging: linear panel copy (source pre-transposed by prep)
  const uint8_t* Tpan = Tq + (size_t)by * 65536;
  const uint8_t* Mpan = Mq + (size_t)bx * 32768;
  const unsigned gT = (unsigned)tid * 16;            // text chunk (8 KB)
  const unsigned gM = (unsigned)(tid & 255) * 16;    // image chunk (4 KB, dup'd)
  const int ldsOff = tid * 16;

  auto stage = [&](int t, int buf) {
    gload_lds16(Tpan + (unsigned)t * 8192 + gT, As8 + buf * 8192 + ldsOff);
    gload_lds16(Mpan + (unsigned)t * 4096 + gM, Bs8 + buf * 8192 + ldsOff);
  };

  // fragment read offsets: one contiguous 1 KB block per wave per fragment
  int toffB[2], moffB[2];
  #pragma unroll
  for (int jt = 0; jt < 2; ++jt)
    toffB[jt] = (tc * 2 + jt) * 1024 + h * 512 + l31 * 16;
  #pragma unroll
  for (int it = 0; it < 2; ++it)
    moffB[it] = ir * 4096 + (ir * 2 + it) * 1024 + h * 512 + l31 * 16;

  f32x16 acc[2][2];
  #pragma unroll
  for (int it = 0; it < 2; ++it)
    #pragma unroll
    for (int jt = 0; jt < 2; ++jt)
      #pragma unroll
      for (int e = 0; e < 16; ++e)
        acc[it][jt][e] = 0.f;

  const int4v z4 = {0, 0, 0, 0};

  // prologue: tiles 0,1 staged; tile 0 resident before first reads
  stage(0, 0); stage(1, 1);
  asm volatile("s_waitcnt vmcnt(2)" ::: "memory");
  __builtin_amdgcn_s_barrier();
  int kt = 0;

#define STEP(BUF, DO_STAGE, VMC)                                               \
  do {                                                                         \
    __builtin_amdgcn_s_barrier();                                              \
    if (DO_STAGE) stage(kt + 2, ((BUF) + 2) % 3);                              \
    asm volatile("s_waitcnt vmcnt(" #VMC ")" ::: "memory");                    \
    int4v tf[2], mf[2];                                                        \
    _Pragma("unroll")                                                          \
    for (int jt = 0; jt < 2; ++jt)                                             \
      tf[jt] = *(const int4v*)(As8 + (BUF) * 8192 + toffB[jt]);                \
    _Pragma("unroll")                                                          \
    for (int it = 0; it < 2; ++it)                                             \
      mf[it] = *(const int4v*)(Bs8 + (BUF) * 8192 + moffB[it]);                \
    __builtin_amdgcn_s_setprio(1);                                             \
    _Pragma("unroll")                                                          \
    for (int it = 0; it < 2; ++it) {                                           \
      const int8v a8 = __builtin_shufflevector(mf[it], z4, 0, 1, 2, 3, 4, 5, 6, 7); \
      _Pragma("unroll")                                                        \
      for (int jt = 0; jt < 2; ++jt) {                                         \
        const int8v b8 = __builtin_shufflevector(tf[jt], z4, 0, 1, 2, 3, 4, 5, 6, 7); \
        acc[it][jt] = __builtin_amdgcn_mfma_scale_f32_32x32x64_f8f6f4(         \
            a8, b8, acc[it][jt], 4, 4, 0, SCALE1, 0, SCALE1);                  \
      }                                                                        \
    }                                                                          \
    __builtin_amdgcn_s_setprio(0);                                             \
    ++kt;                                                                      \
  } while (0)

  STEP(0, true,  4);   // kt=0: stages tile 2
  STEP(1, true,  4);   // kt=1: tile 3
  STEP(2, true,  4);   // kt=2: tile 4
  STEP(0, true,  4);   // kt=3: tile 5
  STEP(1, true,  4);   // kt=4: tile 6
  STEP(2, true,  4);   // kt=5: tile 7 (last)
  STEP(0, false, 2);   // kt=6: tiles 6,7 outstanding -> wait to 2
  STEP(1, false, 0);   // kt=7: drain
#undef STEP

  // ---- fused epilogue (no atomics) ----
  // acc[it][jt][reg] on lane (l31,h) = 256 * dot(image[bcol+ir*64+it*32+crow],
  //                                              text [brow+tc*64+jt*32+l31])
  // with crow = (reg&3) + 8*(reg>>2) + 4*h.
  float2* red = reinterpret_cast<float2*>(As8);   // 8 KB alias on buf0 (dead)

  float nv[2] = {0.f, 0.f}, tot[2] = {0.f, 0.f};
  const int tlA = tc * 64 + l31;          // jt = 0
  const int tlB = tlA + 32;               // jt = 1
  const float2 tgA = tg_s[tlA];
  const float2 tgB = tg_s[tlB];
  #pragma unroll
  for (int it = 0; it < 2; ++it) {
    #pragma unroll
    for (int reg = 0; reg < 16; ++reg) {
      const int crow = (reg & 3) + 8 * (reg >> 2) + 4 * h;
      const float2 mg = mg_s[ir * 64 + it * 32 + crow];
      const unsigned gm = __float_as_uint(mg.y);
      {
        const float sq = fmaxf(fmaf(acc[it][0][reg], -0.0078125f, tgA.x + mg.x), 0.f);
        const float sim = __builtin_amdgcn_exp2f(-1.4426950408889634f *
                                                 __builtin_amdgcn_sqrtf(sq));
        tot[0] += sim;
        if (__float_as_uint(tgA.y) == gm) nv[0] += sim;
      }
      {
        const float sq = fmaxf(fmaf(acc[it][1][reg], -0.0078125f, tgB.x + mg.x), 0.f);
        const float sim = __builtin_amdgcn_exp2f(-1.4426950408889634f *
                                                 __builtin_amdgcn_sqrtf(sq));
        tot[1] += sim;
        if (__float_as_uint(tgB.y) == gm) nv[1] += sim;
      }
    }
  }
  __syncthreads();   // all waves done with LDS tile bufs before red alias
  const int slot = ir * 2 + h;
  red[slot * 256 + tlA] = make_float2(nv[0], tot[0]);
  red[slot * 256 + tlB] = make_float2(nv[1], tot[1]);
  __syncthreads();
  if (tid < 256) {
    float n = 0.f, d = 0.f;
    #pragma unroll
    for (int s = 0; s < 4; ++s) {
      const float2 v = red[s * 256 + tid];
      n += v.x; d += v.y;
    }
    part[(size_t)bx * Bn + brow + tid] = make_float2(n, d);   // (num, total)
  }
}

// ---------------------------------------------------------------------------
// Kernel 3a: per-row sum over 64 image-panel partials; dv = tot - nv;
// loss term -> block sums. Kernel 3b: final reduce of 32 block sums.
// ---------------------------------------------------------------------------
__global__ __launch_bounds__(256) void finalize1_kernel(
    const float2* __restrict__ part, float* __restrict__ bsum)
{
  const int i = blockIdx.x * 256 + threadIdx.x;
  float nv = 0.f, tv = 0.f;
  #pragma unroll 8
  for (int p = 0; p < 64; ++p) {
    const float2 v = part[(size_t)p * Bn + i];
    nv += v.x; tv += v.y;
  }
  const float dv = tv - nv;
  float li = (nv > 0.f && dv > 0.f)
      ? (__builtin_amdgcn_logf(dv) - __builtin_amdgcn_logf(nv)) * 0.69314718055994531f
      : 0.f;
  #pragma unroll
  for (int off = 32; off >= 1; off >>= 1) li += __shfl_xor(li, off, 64);
  __shared__ float ws4[4];
  if ((threadIdx.x & 63) == 0) ws4[threadIdx.x >> 6] = li;
  __syncthreads();
  if (threadIdx.x == 0) bsum[blockIdx.x] = ws4[0] + ws4[1] + ws4[2] + ws4[3];
}

__global__ void finalize2_kernel(const float* __restrict__ bsum, float* __restrict__ out)
{
  float s = (threadIdx.x < 32) ? bsum[threadIdx.x] : 0.f;
  #pragma unroll
  for (int off = 32; off >= 1; off >>= 1) s += __shfl_xor(s, off, 64);
  if (threadIdx.x == 0) out[0] = s / (float)Bn;
}

// ---------------------------------------------------------------------------
extern "C" void kernel_launch(void* const* d_in, const int* in_sizes, int n_in,
                              void* d_out, int out_size, void* d_ws, size_t ws_size,
                              hipStream_t stream) {
  const float* T = (const float*)d_in[0];
  const float* M = (const float*)d_in[1];
  const int* groups = (const int*)d_in[2];

  char* ws = (char*)d_ws;
  uint8_t* Tq = (uint8_t*)ws;                                   // 2 MB fp4 text (transposed)
  uint8_t* Mq = (uint8_t*)(ws + (size_t)32 * 65536);            // 2 MB fp4 image (transposed)
  float* tn  = (float*)(ws + (size_t)64 * 65536);               // 32 KB
  float* mn  = tn + Bn;                                         // 32 KB
  float2* part = (float2*)(mn + Bn);                            // 4 MB (64 x 8192)
  float* bsum = (float*)(part + (size_t)64 * Bn);               // 128 B

  const int smem_bytes = 3 * 8192 + 3 * 8192 + 256 * 8 + 128 * 8;  // 52224 B
  hipFuncSetAttribute((const void*)gemm_epi_kernel,
                      hipFuncAttributeMaxDynamicSharedMemorySize, smem_bytes);

  prep_kernel<<<512, 256, 0, stream>>>(T, M, Tq, Mq, tn, mn);
  gemm_epi_kernel<<<2048, 512, smem_bytes, stream>>>(Tq, Mq, tn, mn, groups, part);
  finalize1_kernel<<<Bn / 256, 256, 0, stream>>>(part, bsum);
  finalize2_kernel<<<1, 64, 0, stream>>>(bsum, (float*)d_out);
}